// Round 1
// baseline (219.679 us; speedup 1.0000x reference)
//
#include <hip/hip_runtime.h>

// VQ-VAE forward: x [64,64,32,32] f32 (NCHW, C==D), weight [512,64] f32.
// d_out: loss (1) | q_out (4194304, NCHW) | encodings (33554432, [N,K]).
//
// R11 = SGPR-stream rewrite. R10 was LDS-return-path-bound (8 ds_read_b128
// per 64 pk_fma; ~585 LDS cyc vs 256 VALU cyc per CU per dp-iter -> VALUBusy
// 49%). Fix: lane-per-row, x fully register-resident (64 VGPR); codebook
// streamed wave-uniform -> s_load -> SGPR operand of v_pk_fma_f32 (broadcast
// is free at operand-read). Main loop has ZERO LDS traffic.
//  - block = 256 thr (4 waves) x 64 rows; wave wv scans codes [wv*128, +128)
//  - 1024 blocks = 4/CU; __launch_bounds__(256,4) -> 16 waves/CU
//  - dist chain bit-identical to R10: v2f acc over ascending dp (E,O packed),
//    dot = acc[0]+acc[1], dist = (x2 + e2) - 2*dot, strict-< ascending-k,
//    cross-wave lexicographic (chunks ascend with wv) => same indices as R10.
//  - epilogue: wave0 = q gather/store + loss from register x; waves 1-3 =
//    one-hot encodings (peel-3 / aligned v4f / tail-1, as R10); wave0 takes
//    the last 1023 v4f so the store work roughly balances.

#define NROWS 65536
#define DIM 64
#define KCODES 512
#define HW 1024
#define TPB 256
#define RPB 64                      // rows per block (= lanes per wave)
#define NBLOCKS (NROWS / RPB)       // 1024

// d_ws float offsets
#define E2_OFF 0                    // e2 [512]
#define PART_OFF 1024               // partials [1024]

typedef float v2f __attribute__((ext_vector_type(2)));
typedef float v4f __attribute__((ext_vector_type(4)));

__global__ __launch_bounds__(256) void vq_prep(
    const float* __restrict__ w, float* __restrict__ ws)
{
    // e2 only (w is consumed row-major directly now): ascending-d chain
    const int k = blockIdx.x * 256 + threadIdx.x;
    float s = 0.0f;
    for (int d = 0; d < DIM; ++d) {
        const float v = w[k * DIM + d];
        s = __fadd_rn(s, __fmul_rn(v, v));
    }
    ws[E2_OFF + k] = s;
}

__global__ __launch_bounds__(TPB, 4) void vq_main(
    const float* __restrict__ x, const float* __restrict__ w,
    const float* __restrict__ ws, float* __restrict__ out,
    float* __restrict__ partial)
{
    __shared__ float sb[4][RPB];
    __shared__ int   si[4][RPB];
    __shared__ int   idxf[RPB];

    const int t    = threadIdx.x;
    const int lane = t & 63;
    const int wv   = __builtin_amdgcn_readfirstlane(t >> 6);
    const int n0   = blockIdx.x * RPB;
    const int b    = n0 >> 10;        // 1024 % 64 == 0: no b straddle
    const int hw0  = n0 & 1023;

    // ---- load this lane's row (n0 + lane) fully into registers.
    // Per d: lanes read consecutive hw -> coalesced 256 B dword loads.
    // All 4 waves load the same 16 KB tile (L1-hot after wave 0).
    const float* xb = x + (size_t)b * (DIM * HW) + hw0 + lane;
    v2f xv[32];
    #pragma unroll
    for (int dp = 0; dp < 32; ++dp) {
        xv[dp][0] = xb[(size_t)(2 * dp) * HW];
        xv[dp][1] = xb[(size_t)(2 * dp + 1) * HW];
    }

    // ---- x2: same ascending-d mul-then-add chain as R10
    float x2 = 0.0f;
    #pragma unroll
    for (int dp = 0; dp < 32; ++dp) {
        x2 = __fadd_rn(x2, __fmul_rn(xv[dp][0], xv[dp][0]));
        x2 = __fadd_rn(x2, __fmul_rn(xv[dp][1], xv[dp][1]));
    }

    // ---- scan this wave's 128-code chunk; w row-major IS (E,O)-pair order.
    // wr/e2 addresses are wave-uniform -> s_load; w operand rides in SGPRs.
    const int kbase = wv * 128;
    const float* e2p = ws + E2_OFF;

    float best = 3.4e38f;
    int   bidx = 0;
    #pragma unroll 1
    for (int k = 0; k < 128; ++k) {
        const float* wr = w + (kbase + k) * DIM;
        v2f acc = (v2f){0.0f, 0.0f};
        #pragma unroll
        for (int dp = 0; dp < 32; ++dp)
            acc += xv[dp] * ((const v2f*)wr)[dp];     // v_pk_fma_f32 (E,O)
        const float dot  = acc[0] + acc[1];
        const float dist = __fsub_rn(__fadd_rn(x2, e2p[kbase + k]),
                                     __fmul_rn(2.0f, dot));
        if (dist < best) { best = dist; bidx = kbase + k; }  // first-min
    }

    sb[wv][lane] = best;
    si[wv][lane] = bidx;
    __syncthreads();

    // ---- cross-wave argmin: chunk code-ranges ascend with wv, per-chunk is
    // lowest-first => lexicographic scan keeps global lowest index on ties.
    if (t < RPB) {
        float bb = sb[0][t]; int bi = si[0][t];
        #pragma unroll
        for (int j = 1; j < 4; ++j) {
            const float ob = sb[j][t]; const int oi = si[j][t];
            if (ob < bb || (ob == bb && oi < bi)) { bb = ob; bi = oi; }
        }
        idxf[t] = bi;
    }
    __syncthreads();

    float* q = out + 1;
    float* slab = out + 1 + (size_t)NROWS * DIM + (size_t)n0 * KCODES;
    v4f* s4 = (v4f*)(slab + 3);                   // 16B-aligned
    const int nf4 = (RPB * KCODES - 4) / 4;       // 8191

    if (wv == 0) {
        // ---- q gather/store + loss; x from registers (exact same values)
        const int widx = idxf[lane];
        const float* wr = w + widx * DIM;
        float lsum = 0.0f;
        #pragma unroll
        for (int dp = 0; dp < 32; ++dp) {
            const v2f wp = *(const v2f*)(wr + 2 * dp);    // per-lane, L1-hot
            const float dE = __fsub_rn(wp[0], xv[dp][0]); // d ascending: E,O
            lsum = __fadd_rn(lsum, __fmul_rn(dE, dE));
            const float dO = __fsub_rn(wp[1], xv[dp][1]);
            lsum = __fadd_rn(lsum, __fmul_rn(dO, dO));
            q[(size_t)(b * DIM + 2 * dp) * HW + hw0 + lane]     = wp[0];
            q[(size_t)(b * DIM + 2 * dp + 1) * HW + hw0 + lane] = wp[1];
        }
        #pragma unroll
        for (int off = 32; off; off >>= 1) lsum += __shfl_down(lsum, off, 64);
        if (lane == 0) partial[blockIdx.x] = lsum;

        // wave0's encodings share: last 1023 v4f
        for (int f = 7168 + lane; f < nf4; f += 64) {
            const int ii = 3 + 4 * f;
            v4f o;
            #pragma unroll
            for (int cc = 0; cc < 4; ++cc) {
                const int e = ii + cc;
                o[cc] = (idxf[e >> 9] == (e & 511)) ? 1.0f : 0.0f;
            }
            s4[f] = o;
        }
    } else {
        // ---- encodings: slab global float index == 1 mod 4 -> peel 3,
        // aligned v4f middle, tail 1 (same trick as R10)
        const int tt = t - 64;                    // 0..191
        if (tt < 3) slab[tt] = (idxf[0] == tt) ? 1.0f : 0.0f;
        if (tt == 4) slab[RPB * KCODES - 1] = (idxf[RPB - 1] == 511) ? 1.0f : 0.0f;
        for (int f = tt; f < 7168; f += 192) {
            const int ii = 3 + 4 * f;
            v4f o;
            #pragma unroll
            for (int cc = 0; cc < 4; ++cc) {
                const int e = ii + cc;
                o[cc] = (idxf[e >> 9] == (e & 511)) ? 1.0f : 0.0f;
            }
            s4[f] = o;
        }
    }
}

__global__ __launch_bounds__(256) void vq_final(
    const float* __restrict__ partial, float* __restrict__ out)
{
    __shared__ float s[256];
    const int t = threadIdx.x;
    s[t] = (partial[t] + partial[t + 256]) + (partial[t + 512] + partial[t + 768]);
    __syncthreads();
    for (int off = 128; off; off >>= 1) {
        if (t < off) s[t] += s[t + off];
        __syncthreads();
    }
    if (t == 0) {
        const float m = s[0] / 4194304.0f;            // mean over B*H*W*D
        out[0] = __fadd_rn(m, __fmul_rn(0.25f, m));   // z_q + 0.25*z_e
    }
}

extern "C" void kernel_launch(void* const* d_in, const int* in_sizes, int n_in,
                              void* d_out, int out_size, void* d_ws, size_t ws_size,
                              hipStream_t stream) {
    const float* x = (const float*)d_in[0];
    const float* w = (const float*)d_in[1];
    float* out     = (float*)d_out;
    float* ws      = (float*)d_ws;

    vq_prep<<<2, 256, 0, stream>>>(w, ws);
    vq_main<<<NBLOCKS, TPB, 0, stream>>>(x, w, ws, out, ws + PART_OFF);
    vq_final<<<1, 256, 0, stream>>>(ws + PART_OFF, out);
}